// Round 15
// baseline (402.898 us; speedup 1.0000x reference)
//
#include <hip/hip_runtime.h>
#include <math.h>

#define Nn 8192
#define Cc 256
#define Dd 128
#define CAP 192   // max row degree: mean ~83, max over 8192 rows ~125

typedef float fx4 __attribute__((ext_vector_type(4)));

// DPP rotation-add within each 16-lane row (quarter): 4 VALU instrs, no DS pipe.
template <int CTRL>
__device__ __forceinline__ float dpp_radd(float x) {
  const int y = __builtin_amdgcn_update_dpp(0, __float_as_int(x), CTRL, 0xf, 0xf, false);
  return x + __int_as_float(y);
}
__device__ __forceinline__ float quarter_sum(float x) {
  x = dpp_radd<0x128>(x);  // row_ror:8
  x = dpp_radd<0x124>(x);  // row_ror:4
  x = dpp_radd<0x122>(x);  // row_ror:2
  x = dpp_radd<0x121>(x);  // row_ror:1
  return x;
}

// ---------------- W transpose ----------------
__global__ __launch_bounds__(256) void wt_kernel(const float* __restrict__ W,
                                                 float4* __restrict__ WT) {
  const int t = blockIdx.x * 256 + threadIdx.x;
  const int c4 = t >> 7;
  const int d  = t & 127;
  const float4 v = *(const float4*)(W + (size_t)d * Cc + c4 * 4);
  WT[c4 * Dd + d] = v;
}

// ---------------- h = x @ W^T ----------------
__global__ __launch_bounds__(256) void h_kernel(const float* __restrict__ x,
                                                const float4* __restrict__ WT,
                                                float* __restrict__ h) {
  const int tid = threadIdx.x;
  const int d = tid & 127;
  const int g = tid >> 7;
  const int r0 = blockIdx.x * 16 + g * 8;
  const float4* x4 = (const float4*)(x + (size_t)r0 * Cc);

  float acc[8];
#pragma unroll
  for (int r = 0; r < 8; ++r) acc[r] = 0.f;
#pragma unroll 4
  for (int c4 = 0; c4 < Cc / 4; ++c4) {
    const float4 w = WT[c4 * Dd + d];
#pragma unroll
    for (int r = 0; r < 8; ++r) {
      const float4 u = x4[r * (Cc / 4) + c4];
      acc[r] += u.x * w.x + u.y * w.y + u.z * w.z + u.w * w.w;
    }
  }
#pragma unroll
  for (int r = 0; r < 8; ++r) h[(size_t)(r0 + r) * Dd + d] = acc[r];
}

#define COMPACT(comp, cidx)                                             \
  {                                                                     \
    const unsigned long long mk = __ballot((comp) != 0.f);              \
    if (mk) {                                                           \
      const int p = cnt + __popcll(mk & lmask);                         \
      if ((comp) != 0.f && p < CAP) idx[p] = col + (cidx);              \
      cnt += __popcll(mk);                                              \
    }                                                                   \
  }

__device__ __forceinline__ void tail_load(int s, int m, const int* idx, int i,
                                          const float* __restrict__ h, int q, int ql,
                                          float4& hvA, float4& hvB) {
  const int e = s * 4 + q;
  const int j = (e < m) ? idx[e] : i;            // safe dummy row
  hvA = *(const float4*)(h + (size_t)j * Dd + ql * 8);
  hvB = *(const float4*)(h + (size_t)j * Dd + ql * 8 + 4);
}

__device__ __forceinline__ void tail_consume(int s, int m, int q,
                                             const float4& hvA, const float4& hvB,
                                             const float4& hiA, const float4& hiB,
                                             float& M, float& L,
                                             float4& accA, float4& accB) {
  float pd = hiA.x * hvA.x + hiA.y * hvA.y + hiA.z * hvA.z + hiA.w * hvA.w
           + hiB.x * hvB.x + hiB.y * hvB.y + hiB.z * hvB.z + hiB.w * hvB.w;
  pd = quarter_sum(pd);                          // quarter-uniform full dot
  const int e = s * 4 + q;
  const float sc = (e < m) ? pd : 0.f;
  if (sc != 0.f) {                               // ref: s==0 -> masked
    const float newM = fmaxf(M, sc);
    const float scale = __expf(M - newM);        // first edge: exp(-inf)=0
    const float p = __expf(sc - newM);
    L = L * scale + p;
    accA.x = accA.x * scale + p * hvA.x;  accA.y = accA.y * scale + p * hvA.y;
    accA.z = accA.z * scale + p * hvA.z;  accA.w = accA.w * scale + p * hvA.w;
    accB.x = accB.x * scale + p * hvB.x;  accB.y = accB.y * scale + p * hvB.y;
    accB.z = accB.z * scale + p * hvB.z;  accB.w = accB.w * scale + p * hvB.w;
    M = newM;
  }
}

__device__ __forceinline__ void merge_write(int i, const float* __restrict__ bias,
                                            float* __restrict__ out, int q, int ql,
                                            float M, float L, float4 accA, float4 accB) {
#pragma unroll
  for (int off = 16; off <= 32; off <<= 1) {
    const float Mo = __shfl_xor(M, off);
    const float Lo = __shfl_xor(L, off);
    float4 aAo, aBo;
    aAo.x = __shfl_xor(accA.x, off); aAo.y = __shfl_xor(accA.y, off);
    aAo.z = __shfl_xor(accA.z, off); aAo.w = __shfl_xor(accA.w, off);
    aBo.x = __shfl_xor(accB.x, off); aBo.y = __shfl_xor(accB.y, off);
    aBo.z = __shfl_xor(accB.z, off); aBo.w = __shfl_xor(accB.w, off);
    const float Mm = fmaxf(M, Mo);
    const float s0 = (M  > -INFINITY) ? __expf(M  - Mm) : 0.f;  // empty-quarter guard
    const float s1 = (Mo > -INFINITY) ? __expf(Mo - Mm) : 0.f;
    L = L * s0 + Lo * s1;
    accA.x = accA.x * s0 + aAo.x * s1;  accA.y = accA.y * s0 + aAo.y * s1;
    accA.z = accA.z * s0 + aAo.z * s1;  accA.w = accA.w * s0 + aAo.w * s1;
    accB.x = accB.x * s0 + aBo.x * s1;  accB.y = accB.y * s0 + aBo.y * s1;
    accB.z = accB.z * s0 + aBo.z * s1;  accB.w = accB.w * s0 + aBo.w * s1;
    M = Mm;
  }
  const float inv = 1.f / L;
  if (q == 0) {
    const float4 bA = *(const float4*)(bias + ql * 8);
    const float4 bB = *(const float4*)(bias + ql * 8 + 4);
    float4 oA, oB;
    oA.x = accA.x * inv + bA.x;  oA.y = accA.y * inv + bA.y;
    oA.z = accA.z * inv + bA.z;  oA.w = accA.w * inv + bA.w;
    oB.x = accB.x * inv + bB.x;  oB.y = accB.y * inv + bB.y;
    oB.z = accB.z * inv + bB.z;  oB.w = accB.w * inv + bB.w;
    *(float4*)(out + (size_t)i * Dd + ql * 8)     = oA;
    *(float4*)(out + (size_t)i * Dd + ql * 8 + 4) = oB;
  }
}

// ---------------- FUSED, 2 ROWS/WAVE, load->consume lag pipeline -----------
// Wave: stream+compact row A; then stream row B with tail-A interleaved at a
// ONE-ITERATION lag: iteration it issues tail-A load(it) BEFORE B's NT refill
// and consumes tail-A step it-1 AFTER the ballots — so the consume's waitcnt
// (vmcnt retires in issue order) drains only loads OLDER than B's latest
// prefetches, never the prefetch queue itself (r13's bug). Tail-B exposed.
__global__ __launch_bounds__(256, 4) void gat_fused(const float* __restrict__ graph,
                                                    const float* __restrict__ h,
                                                    const float* __restrict__ bias,
                                                    float* __restrict__ out) {
  __shared__ int idxs[8][CAP];
  const int wv   = threadIdx.x >> 6;
  const int lane = threadIdx.x & 63;
  const int q    = lane >> 4;
  const int ql   = lane & 15;
  const int iA = blockIdx.x * 8 + wv * 2;
  const int iB = iA + 1;
  int* idxA = idxs[wv * 2];
  int* idxB = idxs[wv * 2 + 1];
  const unsigned long long lmask = (1ull << lane) - 1ull;

  const float4 hiA_A = *(const float4*)(h + (size_t)iA * Dd + ql * 8);
  const float4 hiB_A = *(const float4*)(h + (size_t)iA * Dd + ql * 8 + 4);
  const float4 hiA_B = *(const float4*)(h + (size_t)iB * Dd + ql * 8);
  const float4 hiB_B = *(const float4*)(h + (size_t)iB * Dd + ql * 8 + 4);

  // ---- Phase 1A: stream + compact row A (rolling 8-deep NT prefetch) ----
  int mA;
  {
    const fx4* row = (const fx4*)(graph + (size_t)iA * Nn);
    int* idx = idxA;
    int cnt = 0;
    fx4 v[8];
#pragma unroll
    for (int t = 0; t < 8; ++t)
      v[t] = __builtin_nontemporal_load(&row[t * 64 + lane]);
#pragma unroll
    for (int c = 0; c < 4; ++c) {
#pragma unroll
      for (int t = 0; t < 8; ++t) {
        const fx4 cur = v[t];
        if (c < 3)
          v[t] = __builtin_nontemporal_load(&row[(c + 1) * 8 * 64 + t * 64 + lane]);
        const int col = 4 * ((c * 8 + t) * 64 + lane);
        COMPACT(cur.x, 0) COMPACT(cur.y, 1) COMPACT(cur.z, 2) COMPACT(cur.w, 3)
      }
    }
    mA = min(cnt, CAP);
  }
  const int nsA = (mA + 3) >> 2;

  // ---- Phase 1B + tail-A, software-pipelined ----
  float MA = -INFINITY, LA = 0.f;
  float4 accA_A = {0.f, 0.f, 0.f, 0.f}, accB_A = {0.f, 0.f, 0.f, 0.f};
  float4 tA[2], tB[2];                 // tail double buffer (compile-time slots)
  int mB;
  {
    const fx4* row = (const fx4*)(graph + (size_t)iB * Nn);
    int* idx = idxB;
    int cnt = 0;
    fx4 v[8];
#pragma unroll
    for (int t = 0; t < 8; ++t)
      v[t] = __builtin_nontemporal_load(&row[t * 64 + lane]);
#pragma unroll
    for (int c = 0; c < 4; ++c) {
#pragma unroll
      for (int t = 0; t < 8; ++t) {
        const int it = c * 8 + t;
        // (1) tail-A load for step `it` — issued BEFORE this iteration's refill
        if (it < nsA)
          tail_load(it, mA, idxA, iA, h, q, ql, tA[it & 1], tB[it & 1]);
        // (2) stream refill (NT, stays younger than the tail load above)
        const fx4 cur = v[t];
        if (c < 3)
          v[t] = __builtin_nontemporal_load(&row[(c + 1) * 8 * 64 + t * 64 + lane]);
        // (3) ballot compact (VALU/SALU/LDS only)
        const int col = 4 * ((c * 8 + t) * 64 + lane);
        COMPACT(cur.x, 0) COMPACT(cur.y, 1) COMPACT(cur.z, 2) COMPACT(cur.w, 3)
        // (4) consume tail-A step it-1 (loads are older than all refills issued
        //     since -> waitcnt leaves the prefetch queue intact)
        if (it >= 1 && (it - 1) < nsA)
          tail_consume(it - 1, mA, q, tA[(it - 1) & 1], tB[(it - 1) & 1],
                       hiA_A, hiB_A, MA, LA, accA_A, accB_A);
      }
    }
    mB = min(cnt, CAP);
  }
  if (31 < nsA)                        // consume the last scheduled step
    tail_consume(31, mA, q, tA[31 & 1], tB[31 & 1], hiA_A, hiB_A, MA, LA, accA_A, accB_A);
  for (int s = 32; s < nsA; ++s) {     // leftovers (m > 128: essentially never)
    float4 a, b;
    tail_load(s, mA, idxA, iA, h, q, ql, a, b);
    tail_consume(s, mA, q, a, b, hiA_A, hiB_A, MA, LA, accA_A, accB_A);
  }
  merge_write(iA, bias, out, q, ql, MA, LA, accA_A, accB_A);

  // ---- tail-B (exposed), batch-2 with prefetch ----
  float MB = -INFINITY, LB = 0.f;
  float4 accA_B = {0.f, 0.f, 0.f, 0.f}, accB_B = {0.f, 0.f, 0.f, 0.f};
  const int nsB = (mB + 3) >> 2;
  float4 uA[2], uB[2];
#pragma unroll
  for (int u = 0; u < 2; ++u)
    tail_load(u, mB, idxB, iB, h, q, ql, uA[u], uB[u]);
  const int nbb = (nsB + 1) >> 1;
  for (int b = 0; b < nbb; ++b) {
    float4 nA[2], nB[2];
    if (b + 1 < nbb) {
#pragma unroll
      for (int u = 0; u < 2; ++u)
        tail_load((b + 1) * 2 + u, mB, idxB, iB, h, q, ql, nA[u], nB[u]);
    }
#pragma unroll
    for (int u = 0; u < 2; ++u)
      tail_consume(b * 2 + u, mB, q, uA[u], uB[u], hiA_B, hiB_B, MB, LB, accA_B, accB_B);
#pragma unroll
    for (int u = 0; u < 2; ++u) { uA[u] = nA[u]; uB[u] = nB[u]; }
  }
  merge_write(iB, bias, out, q, ql, MB, LB, accA_B, accB_B);
}

extern "C" void kernel_launch(void* const* d_in, const int* in_sizes, int n_in,
                              void* d_out, int out_size, void* d_ws, size_t ws_size,
                              hipStream_t stream) {
  const float* x     = (const float*)d_in[0];  // [1,8192,256]
  const float* graph = (const float*)d_in[1];  // [8192,8192]
  const float* W     = (const float*)d_in[2];  // [128,256]
  const float* bias  = (const float*)d_in[3];  // [128]
  float* out = (float*)d_out;                  // [1,8192,128]

  // ws layout: h (4 MB @ 0) | WT (128 KB @ 16 MB)
  float*  h  = (float*)d_ws;
  float4* WT = (float4*)((char*)d_ws + (16u << 20));

  wt_kernel<<<32, 256, 0, stream>>>(W, WT);
  h_kernel<<<Nn / 16, 256, 0, stream>>>(x, WT, h);
  gat_fused<<<Nn / 8, 256, 0, stream>>>(graph, h, bias, out);
}